// Round 1
// 486.069 us; speedup vs baseline: 1.0532x; 1.0532x over previous
//
#include <hip/hip_runtime.h>
#include <hip/hip_bf16.h>

#define T_TOTAL 262144
#define B_SEG   4096

typedef __attribute__((ext_vector_type(8))) short short8;
typedef __attribute__((ext_vector_type(4))) float f32x4;

__device__ __forceinline__ short f2bf(float x) {
    __hip_bfloat16 h = __float2bfloat16(x);
    return *reinterpret_cast<short*>(&h);
}
__device__ __forceinline__ float bf2f(short s) {
    unsigned u = ((unsigned)(unsigned short)s) << 16;
    return __uint_as_float(u);
}

// ---------------------------------------------------------------------------
// transpose_weights: W1,W2,W3v (fp32 [K][N]) -> bf16 [N][K] via LDS 64x64 tiles
// grid: 40 blocks x 256 thr. blocks 0-7: W1(2x4), 8-23: W2(4x4), 24-39: W3v(4x4)
// ---------------------------------------------------------------------------
__global__ __launch_bounds__(256) void transpose_weights(
    const float* __restrict__ W1, const float* __restrict__ W2,
    const float* __restrict__ W3,
    short* __restrict__ W1T, short* __restrict__ W2T, short* __restrict__ W3vT) {
    __shared__ float t[64][68];
    const int b = blockIdx.x, tid = threadIdx.x;
    const float* src; short* dst;
    int k0, n0_src, n0_dst, sstride, dstride;
    if (b < 8) {
        int kt = b >> 2, nt = b & 3;
        src = W1; dst = W1T; sstride = 256; dstride = 128;
        k0 = kt * 64; n0_src = nt * 64; n0_dst = nt * 64;
    } else if (b < 24) {
        int id = b - 8, kt = id >> 2, nt = id & 3;
        src = W2; dst = W2T; sstride = 256; dstride = 256;
        k0 = kt * 64; n0_src = nt * 64; n0_dst = nt * 64;
    } else {
        int id = b - 24, kt = id >> 2, nt = id & 3;
        src = W3; dst = W3vT; sstride = 512; dstride = 256;
        k0 = kt * 64; n0_src = 256 + nt * 64; n0_dst = nt * 64;
    }
    // read 64x64 fp32 tile, coalesced
    {
        int r = tid >> 4, c4 = (tid & 15) * 4;
#pragma unroll
        for (int p = 0; p < 4; p++) {
            int k = p * 16 + r;
            float4 v = *reinterpret_cast<const float4*>(&src[(size_t)(k0 + k) * sstride + n0_src + c4]);
            *reinterpret_cast<float4*>(&t[k][c4]) = v;
        }
    }
    __syncthreads();
    // write transposed bf16: thread -> n = tid>>2, kq = tid&3 (16 k each)
    {
        int n = tid >> 2, kq = tid & 3;
        short8 s0, s1;
#pragma unroll
        for (int i = 0; i < 8; i++) s0[i] = f2bf(t[kq * 16 + i][n]);
#pragma unroll
        for (int i = 0; i < 8; i++) s1[i] = f2bf(t[kq * 16 + 8 + i][n]);
        short* o = &dst[(size_t)(n0_dst + n) * dstride + k0 + kq * 16];
        *reinterpret_cast<short8*>(o) = s0;
        *reinterpret_cast<short8*>(o + 8) = s1;
    }
}

// ---------------------------------------------------------------------------
// vec_kernel: bz[j] = W3[j,:256].bq ; wc[c] = Wq[c,:].b3[:256] ; c0 = bq.b3[:256]
// ---------------------------------------------------------------------------
__global__ __launch_bounds__(256) void vec_kernel(
    const float* __restrict__ Wq, const float* __restrict__ W3,
    const float* __restrict__ bq, const float* __restrict__ b3,
    float* __restrict__ bz, float* __restrict__ wc, float* __restrict__ c0) {
    const int tid = threadIdx.x;
    if (blockIdx.x == 0) {
        float s = 0.f;
        for (int n = 0; n < 256; n += 4) {
            float4 a = *reinterpret_cast<const float4*>(&W3[(size_t)tid * 512 + n]);
            float4 b = *reinterpret_cast<const float4*>(&bq[n]);
            s += a.x * b.x + a.y * b.y + a.z * b.z + a.w * b.w;
        }
        bz[tid] = s;
    } else {
#pragma unroll
        for (int h = 0; h < 2; h++) {
            int c = h * 256 + tid;
            float s = 0.f;
            for (int n = 0; n < 256; n += 4) {
                float4 a = *reinterpret_cast<const float4*>(&Wq[(size_t)c * 256 + n]);
                float4 b = *reinterpret_cast<const float4*>(&b3[n]);
                s += a.x * b.x + a.y * b.y + a.z * b.z + a.w * b.w;
            }
            wc[c] = s;
        }
        if (tid == 0) {
            float s = 0.f;
            for (int n = 0; n < 256; n++) s += bq[n] * b3[n];
            c0[0] = s;
        }
    }
}

// ---------------------------------------------------------------------------
// prep_wqz: Wqz[c][j] = sum_n Wq[c][n] * W3[j][n]  (fp32, 512x256)
// 512 blocks: 16c x 16j tile each
// ---------------------------------------------------------------------------
__global__ __launch_bounds__(256) void prep_wqz(
    const float* __restrict__ Wq, const float* __restrict__ W3,
    float* __restrict__ Wqz) {
    __shared__ float wq[16][260];
    __shared__ float w3[16][260];
    const int tid = threadIdx.x;
    const int c0 = (blockIdx.x >> 4) * 16, j0 = (blockIdx.x & 15) * 16;
    {
        int r = tid >> 4, nq = tid & 15;
#pragma unroll
        for (int p = 0; p < 4; p++) {
            int col = nq * 4 + p * 64;
            *reinterpret_cast<float4*>(&wq[r][col]) =
                *reinterpret_cast<const float4*>(&Wq[(size_t)(c0 + r) * 256 + col]);
            *reinterpret_cast<float4*>(&w3[r][col]) =
                *reinterpret_cast<const float4*>(&W3[(size_t)(j0 + r) * 512 + col]);
        }
    }
    __syncthreads();
    const int ci = tid >> 4, ji = tid & 15;
    float s = 0.f;
    for (int n = 0; n < 256; n += 4) {
        float4 a = *reinterpret_cast<const float4*>(&wq[ci][n]);
        float4 b = *reinterpret_cast<const float4*>(&w3[ji][n]);
        s += a.x * b.x + a.y * b.y + a.z * b.z + a.w * b.w;
    }
    Wqz[(size_t)(c0 + ci) * 256 + j0 + ji] = s;
}

// ---------------------------------------------------------------------------
// zq_kernel: ZQ = context @ Wqz + bz  (fp32 [4096][256]); 64x64 tile SGEMM
// grid (64, 4); A staged via LDS (transposed), B read from L2 (broadcast-y)
// ---------------------------------------------------------------------------
__global__ __launch_bounds__(256) void zq_kernel(
    const float* __restrict__ ctx, const float* __restrict__ Wqz,
    const float* __restrict__ bz, float* __restrict__ zq) {
    __shared__ float As[2][16][68];
    const int tid = threadIdx.x;
    const int tm = tid & 15, tn = tid >> 4;
    const int row0 = blockIdx.x * 64, col0 = blockIdx.y * 64;
    const int lr = tid >> 2, lk = tid & 3;

    float acc[4][4];
#pragma unroll
    for (int i = 0; i < 4; i++)
#pragma unroll
        for (int j = 0; j < 4; j++) acc[i][j] = 0.f;

    float4 av = *reinterpret_cast<const float4*>(&ctx[(size_t)(row0 + lr) * 512 + lk * 4]);
    for (int c = 0; c < 32; c++) {
        int cur = c & 1;
        As[cur][lk * 4 + 0][lr] = av.x;
        As[cur][lk * 4 + 1][lr] = av.y;
        As[cur][lk * 4 + 2][lr] = av.z;
        As[cur][lk * 4 + 3][lr] = av.w;
        __syncthreads();
        if (c < 31)
            av = *reinterpret_cast<const float4*>(
                &ctx[(size_t)(row0 + lr) * 512 + (c + 1) * 16 + lk * 4]);
#pragma unroll
        for (int k = 0; k < 16; k++) {
            float4 a = *reinterpret_cast<const float4*>(&As[cur][k][tm * 4]);
            float4 b = *reinterpret_cast<const float4*>(
                &Wqz[(size_t)(c * 16 + k) * 256 + col0 + tn * 4]);
#pragma unroll
            for (int i = 0; i < 4; i++) {
                float ai = (i == 0) ? a.x : (i == 1) ? a.y : (i == 2) ? a.z : a.w;
                acc[i][0] += ai * b.x; acc[i][1] += ai * b.y;
                acc[i][2] += ai * b.z; acc[i][3] += ai * b.w;
            }
        }
    }
    float4 bv = *reinterpret_cast<const float4*>(&bz[col0 + tn * 4]);
#pragma unroll
    for (int i = 0; i < 4; i++) {
        float4 o = {acc[i][0] + bv.x, acc[i][1] + bv.y, acc[i][2] + bv.z, acc[i][3] + bv.w};
        *reinterpret_cast<float4*>(&zq[(size_t)(row0 + tm * 4 + i) * 256 + col0 + tn * 4]) = o;
    }
}

// ---------------------------------------------------------------------------
// cvec_kernel: cbuf[s] = ctx[s,:].wc + c0
// ---------------------------------------------------------------------------
__global__ __launch_bounds__(256) void cvec_kernel(
    const float* __restrict__ ctx, const float* __restrict__ wc,
    const float* __restrict__ c0, float* __restrict__ cbuf) {
    const int tid = threadIdx.x;
    const int row = blockIdx.x * 32 + (tid >> 3);
    const int l = tid & 7;
    float s = 0.f;
    for (int i = 0; i < 64; i += 4) {
        float4 a = *reinterpret_cast<const float4*>(&ctx[(size_t)row * 512 + l * 64 + i]);
        float4 b = *reinterpret_cast<const float4*>(&wc[l * 64 + i]);
        s += a.x * b.x + a.y * b.y + a.z * b.z + a.w * b.w;
    }
    s += __shfl_xor(s, 1); s += __shfl_xor(s, 2); s += __shfl_xor(s, 4);
    if (l == 0) cbuf[row] = s + c0[0];
}

// ---------------------------------------------------------------------------
// mlp_kernel: fused MLP, M=128, 8 waves (2M x 4N), single 64KB act buffer.
// Swizzle (all K): elem(m,k) at m*K + ((k>>3)^(m&15))*8 + (k&7).
// MFMA operand swap: D = W_frag x act_frag -> lane holds 4 consecutive n.
// logits folded into layer-2 epilogue via zq (no k-GEMM).
//
// Register budget note: __launch_bounds__(512,4) = 128 unified VGPR+AGPR.
// acc (64, AGPR) + W double-buffer (32) + A single-buffer (16) + 32-bit
// addressing (~6) fits; the previous version double-buffered BOTH operands
// (demand ~150) and spilled ~20 hot regs to scratch (WRITE_SIZE 2.4x).
// ---------------------------------------------------------------------------
template <int K>
__device__ __forceinline__ void run_layer(
    const short* __restrict__ act, const short* __restrict__ Wt,
    int mbase, int nbase, int l16, int quad, f32x4 acc[4][4]) {
    constexpr int KK = K / 32;
    const f32x4 zero = {0.f, 0.f, 0.f, 0.f};
#pragma unroll
    for (int i = 0; i < 4; i++)
#pragma unroll
        for (int j = 0; j < 4; j++) acc[i][j] = zero;

    // 32-bit byte offsets; Wt stays an SGPR base (saddr + voffset form).
    int woff[4];
#pragma unroll
    for (int ns = 0; ns < 4; ns++)
        woff[ns] = ((nbase + ns * 16 + l16) * K + quad * 8) * 2;
    // single LDS base; ms sub-tiles via compile-time ds offset (ms*16*K*2 <= 24576)
    const int abase = (mbase + l16) * K * 2;
    const char* actc = reinterpret_cast<const char*>(act);
    const char* wtc  = reinterpret_cast<const char*>(Wt);

    short8 wbuf[2][4];   // W double-buffered (L2 latency)
    short8 areg[4];      // A single-buffered (LDS latency, hidden by TLP)

#pragma unroll
    for (int ns = 0; ns < 4; ns++)
        wbuf[0][ns] = *reinterpret_cast<const short8*>(wtc + woff[ns]);

#pragma unroll
    for (int kk = 0; kk < KK; kk++) {
        // prefetch next W tile (kk+1 folds into the 13-bit global imm offset)
        if (kk + 1 < KK) {
#pragma unroll
            for (int ns = 0; ns < 4; ns++)
                wbuf[(kk + 1) & 1][ns] = *reinterpret_cast<const short8*>(
                    wtc + woff[ns] + (kk + 1) * 64);
        }
        // JIT A fragments from LDS (swizzled)
        {
            const int sg = (((kk * 4 + quad) ^ l16) * 16);
#pragma unroll
            for (int ms = 0; ms < 4; ms++)
                areg[ms] = *reinterpret_cast<const short8*>(
                    actc + abase + ms * 16 * K * 2 + sg);
        }
        const int cb = kk & 1;
#pragma unroll
        for (int ms = 0; ms < 4; ms++)
#pragma unroll
            for (int ns = 0; ns < 4; ns++)
                acc[ms][ns] = __builtin_amdgcn_mfma_f32_16x16x32_bf16(
                    wbuf[cb][ns], areg[ms], acc[ms][ns], 0, 0, 0);
    }
}

__global__ __launch_bounds__(512, 4) void mlp_kernel(
    const float* __restrict__ objects, const int* __restrict__ seg_ids,
    const short* __restrict__ W1T, const short* __restrict__ W2T,
    const short* __restrict__ W3vT,
    const float* __restrict__ b1, const float* __restrict__ b2,
    const float* __restrict__ b3,
    const float* __restrict__ zqbuf, const float* __restrict__ cbuf,
    float* __restrict__ logits_out, short* __restrict__ vout) {
    __shared__ __align__(16) short bufH[128 * 256];   // 64 KB: X -> h1 -> h2 -> v
    __shared__ float slots[4][128];

    const int tid  = threadIdx.x;
    const int wave = tid >> 6;
    const int lane = tid & 63;
    const int quad = lane >> 4;
    const int l16  = lane & 15;
    const int mbase = (wave & 1) * 64;
    const int wn    = wave >> 1;
    const int nbase = wn * 64;
    const int row0  = blockIdx.x * 128;

    // ---- stage X (fp32 -> bf16, K=128 swizzled layout in bufH[0:32KB])
    {
        const float4* op = reinterpret_cast<const float4*>(objects + (size_t)row0 * 128);
#pragma unroll
        for (int i = 0; i < 4; i++) {
            int u = tid + i * 512;           // 0..2047: m = u>>4, kg = u&15
            int m = u >> 4, kg = u & 15;
            float4 x0 = op[u * 2];
            float4 x1 = op[u * 2 + 1];
            short8 s;
            s[0] = f2bf(x0.x); s[1] = f2bf(x0.y); s[2] = f2bf(x0.z); s[3] = f2bf(x0.w);
            s[4] = f2bf(x1.x); s[5] = f2bf(x1.y); s[6] = f2bf(x1.z); s[7] = f2bf(x1.w);
            *reinterpret_cast<short8*>(&bufH[m * 128 + ((kg ^ (m & 15)) * 8)]) = s;
        }
    }
    __syncthreads();

    f32x4 acc[4][4];

    auto store_act = [&](const float* __restrict__ bias) {
#pragma unroll
        for (int ns = 0; ns < 4; ns++) {
            int n0 = nbase + ns * 16 + quad * 4;
            float4 bv = *reinterpret_cast<const float4*>(&bias[n0]);
#pragma unroll
            for (int ms = 0; ms < 4; ms++) {
                int m = mbase + ms * 16 + l16;
                short4 s;
                s.x = f2bf(fmaxf(acc[ms][ns][0] + bv.x, 0.f));
                s.y = f2bf(fmaxf(acc[ms][ns][1] + bv.y, 0.f));
                s.z = f2bf(fmaxf(acc[ms][ns][2] + bv.z, 0.f));
                s.w = f2bf(fmaxf(acc[ms][ns][3] + bv.w, 0.f));
                *reinterpret_cast<short4*>(
                    &bufH[m * 256 + (((n0 >> 3) ^ (m & 15)) * 8) + (n0 & 7)]) = s;
            }
        }
    };

    // ---- layer 1: h1 = relu(X @ W1 + b1)
    run_layer<128>(bufH, W1T, mbase, nbase, l16, quad, acc);
    __syncthreads();                 // X fully consumed
    store_act(b1);
    __syncthreads();

    // ---- layer 2: h2 = relu(h1 @ W2 + b2); fold logits = h2.zq[seg]
    run_layer<256>(bufH, W2T, mbase, nbase, l16, quad, acc);
    __syncthreads();                 // h1 fully consumed
    {
        float part[4] = {0.f, 0.f, 0.f, 0.f};
        int segm[4];
#pragma unroll
        for (int ms = 0; ms < 4; ms++) segm[ms] = seg_ids[row0 + mbase + ms * 16 + l16];
#pragma unroll
        for (int ns = 0; ns < 4; ns++) {
            int n0 = nbase + ns * 16 + quad * 4;
            float4 bv = *reinterpret_cast<const float4*>(&b2[n0]);
#pragma unroll
            for (int ms = 0; ms < 4; ms++) {
                int m = mbase + ms * 16 + l16;
                float h0 = fmaxf(acc[ms][ns][0] + bv.x, 0.f);
                float h1v = fmaxf(acc[ms][ns][1] + bv.y, 0.f);
                float h2v = fmaxf(acc[ms][ns][2] + bv.z, 0.f);
                float h3 = fmaxf(acc[ms][ns][3] + bv.w, 0.f);
                short4 s;
                s.x = f2bf(h0); s.y = f2bf(h1v); s.z = f2bf(h2v); s.w = f2bf(h3);
                *reinterpret_cast<short4*>(
                    &bufH[m * 256 + (((n0 >> 3) ^ (m & 15)) * 8) + (n0 & 7)]) = s;
                float4 zq4 = *reinterpret_cast<const float4*>(
                    &zqbuf[(size_t)segm[ms] * 256 + n0]);
                part[ms] += h0 * zq4.x + h1v * zq4.y + h2v * zq4.z + h3 * zq4.w;
            }
        }
#pragma unroll
        for (int ms = 0; ms < 4; ms++) {
            float p = part[ms];
            p += __shfl_xor(p, 16);
            p += __shfl_xor(p, 32);
            if (quad == 0) slots[wn][mbase + ms * 16 + l16] = p;
        }
    }
    __syncthreads();
    if (tid < 128) {
        int seg = seg_ids[row0 + tid];
        float s = slots[0][tid] + slots[1][tid] + slots[2][tid] + slots[3][tid] + cbuf[seg];
        logits_out[row0 + tid] = s * 0.0625f;   // / sqrt(256)
    }

    // ---- layer 3 v-half: v = h2 @ W3v + b3v
    run_layer<256>(bufH, W3vT, mbase, nbase, l16, quad, acc);
    __syncthreads();                 // h2 fully consumed
#pragma unroll
    for (int ns = 0; ns < 4; ns++) {
        int n0 = nbase + ns * 16 + quad * 4;
        float4 bv = *reinterpret_cast<const float4*>(&b3[256 + n0]);
#pragma unroll
        for (int ms = 0; ms < 4; ms++) {
            int m = mbase + ms * 16 + l16;
            short4 s;
            s.x = f2bf(acc[ms][ns][0] + bv.x);
            s.y = f2bf(acc[ms][ns][1] + bv.y);
            s.z = f2bf(acc[ms][ns][2] + bv.z);
            s.w = f2bf(acc[ms][ns][3] + bv.w);
            *reinterpret_cast<short4*>(
                &bufH[m * 256 + (((n0 >> 3) ^ (m & 15)) * 8) + (n0 & 7)]) = s;
        }
    }
    __syncthreads();
    // copy out, un-swizzling
#pragma unroll
    for (int i = 0; i < 8; i++) {
        int idx = tid + i * 512;          // [0,4096): m = idx>>5, sg = idx&31
        int m = idx >> 5, sg = idx & 31;
        short8 val = *reinterpret_cast<const short8*>(&bufH[m * 256 + sg * 8]);
        int n0 = (sg ^ (m & 15)) * 8;
        *reinterpret_cast<short8*>(&vout[(size_t)(row0 + m) * 256 + n0]) = val;
    }
}

// ---------------------------------------------------------------------------
// segment_kernel: per-segment softmax + weighted sum of v
// ---------------------------------------------------------------------------
__global__ __launch_bounds__(256) void segment_kernel(
    const float* __restrict__ logits, const short* __restrict__ vbuf,
    const int* __restrict__ seg_ids, float* __restrict__ emb,
    float* __restrict__ wout) {
    const int b = blockIdx.x;
    const int tid = threadIdx.x;
    __shared__ int range[2];
    __shared__ float wred[4];
    __shared__ float slots[4][256];

    if (tid < 2) {
        int target = b + tid;
        int lo = 0, hi = T_TOTAL;
        while (lo < hi) {
            int mid = (lo + hi) >> 1;
            if (seg_ids[mid] < target) lo = mid + 1; else hi = mid;
        }
        range[tid] = lo;
    }
    __syncthreads();
    const int start = range[0], end = range[1];

    float mx = -1e30f;
    for (int t = start + tid; t < end; t += 256) mx = fmaxf(mx, logits[t]);
#pragma unroll
    for (int off = 32; off >= 1; off >>= 1) mx = fmaxf(mx, __shfl_xor(mx, off));
    if ((tid & 63) == 0) wred[tid >> 6] = mx;
    __syncthreads();
    mx = fmaxf(fmaxf(wred[0], wred[1]), fmaxf(wred[2], wred[3]));
    __syncthreads();

    float s = 0.f;
    for (int t = start + tid; t < end; t += 256) s += __expf(logits[t] - mx);
#pragma unroll
    for (int off = 32; off >= 1; off >>= 1) s += __shfl_xor(s, off);
    if ((tid & 63) == 0) wred[tid >> 6] = s;
    __syncthreads();
    float invz = 1.f / (wred[0] + wred[1] + wred[2] + wred[3]);

    for (int t = start + tid; t < end; t += 256)
        wout[t] = __expf(logits[t] - mx) * invz;

    const int cg = tid & 63, r = tid >> 6;
    float a0 = 0.f, a1 = 0.f, a2 = 0.f, a3 = 0.f;
    for (int t = start + r; t < end; t += 4) {
        float wv = __expf(logits[t] - mx) * invz;
        short4 v4 = *reinterpret_cast<const short4*>(&vbuf[(size_t)t * 256 + cg * 4]);
        a0 += wv * bf2f(v4.x);
        a1 += wv * bf2f(v4.y);
        a2 += wv * bf2f(v4.z);
        a3 += wv * bf2f(v4.w);
    }
    float4 av = {a0, a1, a2, a3};
    *reinterpret_cast<float4*>(&slots[r][cg * 4]) = av;
    __syncthreads();
    emb[(size_t)b * 256 + tid] =
        slots[0][tid] + slots[1][tid] + slots[2][tid] + slots[3][tid];
}

// ---------------------------------------------------------------------------
extern "C" void kernel_launch(void* const* d_in, const int* in_sizes, int n_in,
                              void* d_out, int out_size, void* d_ws, size_t ws_size,
                              hipStream_t stream) {
    const float* objects = (const float*)d_in[0];
    const float* context = (const float*)d_in[1];
    const int*   seg     = (const int*)d_in[2];
    const float* W1 = (const float*)d_in[3];
    const float* b1 = (const float*)d_in[4];
    const float* W2 = (const float*)d_in[5];
    const float* b2 = (const float*)d_in[6];
    const float* W3 = (const float*)d_in[7];
    const float* b3 = (const float*)d_in[8];
    const float* Wq = (const float*)d_in[9];
    const float* bq = (const float*)d_in[10];

    char* ws = (char*)d_ws;
    float* zqbuf = (float*)(ws);                        // 4 MB
    float* cbuf  = (float*)(ws + 4194304);              // 16 KB
    short* W1T   = (short*)(ws + 4210688);              // 64 KB
    short* W2T   = (short*)(ws + 4276224);              // 128 KB
    short* W3vT  = (short*)(ws + 4407296);              // 128 KB
    // logits region (1 MB) doubles as scratch for Wqz/bz/wc/c0 (consumed
    // before mlp_kernel writes logits over it)
    char*  lreg   = ws + 4538368;
    float* logits = (float*)lreg;
    float* Wqz    = (float*)lreg;                       // 512 KB
    float* bz     = (float*)(lreg + 524288);            // 1 KB
    float* wc     = (float*)(lreg + 525312);            // 2 KB
    float* c0     = (float*)(lreg + 527360);            // 16 B
    short* vbuf   = (short*)(ws + 5586944);             // 128 MB

    float* emb  = (float*)d_out;
    float* wout = emb + (size_t)B_SEG * 256;

    transpose_weights<<<40, 256, 0, stream>>>(W1, W2, W3, W1T, W2T, W3vT);
    vec_kernel<<<2, 256, 0, stream>>>(Wq, W3, bq, b3, bz, wc, c0);
    prep_wqz<<<512, 256, 0, stream>>>(Wq, W3, Wqz);
    zq_kernel<<<dim3(64, 4), 256, 0, stream>>>(context, Wqz, bz, zqbuf);
    cvec_kernel<<<128, 256, 0, stream>>>(context, wc, c0, cbuf);
    mlp_kernel<<<T_TOTAL / 128, 512, 0, stream>>>(objects, seg, W1T, W2T, W3vT,
                                                  b1, b2, b3, zqbuf, cbuf,
                                                  logits, vbuf);
    segment_kernel<<<B_SEG, 256, 0, stream>>>(logits, vbuf, seg, emb, wout);
}

// Round 2
// 482.669 us; speedup vs baseline: 1.0606x; 1.0070x over previous
//
#include <hip/hip_runtime.h>
#include <hip/hip_bf16.h>

#define T_TOTAL 262144
#define B_SEG   4096

typedef __attribute__((ext_vector_type(8))) short short8;
typedef __attribute__((ext_vector_type(4))) float f32x4;

__device__ __forceinline__ short f2bf(float x) {
    __hip_bfloat16 h = __float2bfloat16(x);
    return *reinterpret_cast<short*>(&h);
}
__device__ __forceinline__ float bf2f(short s) {
    unsigned u = ((unsigned)(unsigned short)s) << 16;
    return __uint_as_float(u);
}

// ---------------------------------------------------------------------------
// transpose_weights: W1,W2,W3v (fp32 [K][N]) -> bf16 [N][K] via LDS 64x64 tiles
// grid: 40 blocks x 256 thr. blocks 0-7: W1(2x4), 8-23: W2(4x4), 24-39: W3v(4x4)
// ---------------------------------------------------------------------------
__global__ __launch_bounds__(256) void transpose_weights(
    const float* __restrict__ W1, const float* __restrict__ W2,
    const float* __restrict__ W3,
    short* __restrict__ W1T, short* __restrict__ W2T, short* __restrict__ W3vT) {
    __shared__ float t[64][68];
    const int b = blockIdx.x, tid = threadIdx.x;
    const float* src; short* dst;
    int k0, n0_src, n0_dst, sstride, dstride;
    if (b < 8) {
        int kt = b >> 2, nt = b & 3;
        src = W1; dst = W1T; sstride = 256; dstride = 128;
        k0 = kt * 64; n0_src = nt * 64; n0_dst = nt * 64;
    } else if (b < 24) {
        int id = b - 8, kt = id >> 2, nt = id & 3;
        src = W2; dst = W2T; sstride = 256; dstride = 256;
        k0 = kt * 64; n0_src = nt * 64; n0_dst = nt * 64;
    } else {
        int id = b - 24, kt = id >> 2, nt = id & 3;
        src = W3; dst = W3vT; sstride = 512; dstride = 256;
        k0 = kt * 64; n0_src = 256 + nt * 64; n0_dst = nt * 64;
    }
    // read 64x64 fp32 tile, coalesced
    {
        int r = tid >> 4, c4 = (tid & 15) * 4;
#pragma unroll
        for (int p = 0; p < 4; p++) {
            int k = p * 16 + r;
            float4 v = *reinterpret_cast<const float4*>(&src[(size_t)(k0 + k) * sstride + n0_src + c4]);
            *reinterpret_cast<float4*>(&t[k][c4]) = v;
        }
    }
    __syncthreads();
    // write transposed bf16: thread -> n = tid>>2, kq = tid&3 (16 k each)
    {
        int n = tid >> 2, kq = tid & 3;
        short8 s0, s1;
#pragma unroll
        for (int i = 0; i < 8; i++) s0[i] = f2bf(t[kq * 16 + i][n]);
#pragma unroll
        for (int i = 0; i < 8; i++) s1[i] = f2bf(t[kq * 16 + 8 + i][n]);
        short* o = &dst[(size_t)(n0_dst + n) * dstride + k0 + kq * 16];
        *reinterpret_cast<short8*>(o) = s0;
        *reinterpret_cast<short8*>(o + 8) = s1;
    }
}

// ---------------------------------------------------------------------------
// vec_kernel: bz[j] = W3[j,:256].bq ; wc[c] = Wq[c,:].b3[:256] ; c0 = bq.b3[:256]
// ---------------------------------------------------------------------------
__global__ __launch_bounds__(256) void vec_kernel(
    const float* __restrict__ Wq, const float* __restrict__ W3,
    const float* __restrict__ bq, const float* __restrict__ b3,
    float* __restrict__ bz, float* __restrict__ wc, float* __restrict__ c0) {
    const int tid = threadIdx.x;
    if (blockIdx.x == 0) {
        float s = 0.f;
        for (int n = 0; n < 256; n += 4) {
            float4 a = *reinterpret_cast<const float4*>(&W3[(size_t)tid * 512 + n]);
            float4 b = *reinterpret_cast<const float4*>(&bq[n]);
            s += a.x * b.x + a.y * b.y + a.z * b.z + a.w * b.w;
        }
        bz[tid] = s;
    } else {
#pragma unroll
        for (int h = 0; h < 2; h++) {
            int c = h * 256 + tid;
            float s = 0.f;
            for (int n = 0; n < 256; n += 4) {
                float4 a = *reinterpret_cast<const float4*>(&Wq[(size_t)c * 256 + n]);
                float4 b = *reinterpret_cast<const float4*>(&b3[n]);
                s += a.x * b.x + a.y * b.y + a.z * b.z + a.w * b.w;
            }
            wc[c] = s;
        }
        if (tid == 0) {
            float s = 0.f;
            for (int n = 0; n < 256; n++) s += bq[n] * b3[n];
            c0[0] = s;
        }
    }
}

// ---------------------------------------------------------------------------
// prep_wqz: Wqz[c][j] = sum_n Wq[c][n] * W3[j][n]  (fp32, 512x256)
// 512 blocks: 16c x 16j tile each
// ---------------------------------------------------------------------------
__global__ __launch_bounds__(256) void prep_wqz(
    const float* __restrict__ Wq, const float* __restrict__ W3,
    float* __restrict__ Wqz) {
    __shared__ float wq[16][260];
    __shared__ float w3[16][260];
    const int tid = threadIdx.x;
    const int c0 = (blockIdx.x >> 4) * 16, j0 = (blockIdx.x & 15) * 16;
    {
        int r = tid >> 4, nq = tid & 15;
#pragma unroll
        for (int p = 0; p < 4; p++) {
            int col = nq * 4 + p * 64;
            *reinterpret_cast<float4*>(&wq[r][col]) =
                *reinterpret_cast<const float4*>(&Wq[(size_t)(c0 + r) * 256 + col]);
            *reinterpret_cast<float4*>(&w3[r][col]) =
                *reinterpret_cast<const float4*>(&W3[(size_t)(j0 + r) * 512 + col]);
        }
    }
    __syncthreads();
    const int ci = tid >> 4, ji = tid & 15;
    float s = 0.f;
    for (int n = 0; n < 256; n += 4) {
        float4 a = *reinterpret_cast<const float4*>(&wq[ci][n]);
        float4 b = *reinterpret_cast<const float4*>(&w3[ji][n]);
        s += a.x * b.x + a.y * b.y + a.z * b.z + a.w * b.w;
    }
    Wqz[(size_t)(c0 + ci) * 256 + j0 + ji] = s;
}

// ---------------------------------------------------------------------------
// zq_kernel: ZQ = context @ Wqz + bz  (fp32 [4096][256]); 64x64 tile SGEMM
// grid (64, 4); A staged via LDS (transposed), B read from L2 (broadcast-y)
// ---------------------------------------------------------------------------
__global__ __launch_bounds__(256) void zq_kernel(
    const float* __restrict__ ctx, const float* __restrict__ Wqz,
    const float* __restrict__ bz, float* __restrict__ zq) {
    __shared__ float As[2][16][68];
    const int tid = threadIdx.x;
    const int tm = tid & 15, tn = tid >> 4;
    const int row0 = blockIdx.x * 64, col0 = blockIdx.y * 64;
    const int lr = tid >> 2, lk = tid & 3;

    float acc[4][4];
#pragma unroll
    for (int i = 0; i < 4; i++)
#pragma unroll
        for (int j = 0; j < 4; j++) acc[i][j] = 0.f;

    float4 av = *reinterpret_cast<const float4*>(&ctx[(size_t)(row0 + lr) * 512 + lk * 4]);
    for (int c = 0; c < 32; c++) {
        int cur = c & 1;
        As[cur][lk * 4 + 0][lr] = av.x;
        As[cur][lk * 4 + 1][lr] = av.y;
        As[cur][lk * 4 + 2][lr] = av.z;
        As[cur][lk * 4 + 3][lr] = av.w;
        __syncthreads();
        if (c < 31)
            av = *reinterpret_cast<const float4*>(
                &ctx[(size_t)(row0 + lr) * 512 + (c + 1) * 16 + lk * 4]);
#pragma unroll
        for (int k = 0; k < 16; k++) {
            float4 a = *reinterpret_cast<const float4*>(&As[cur][k][tm * 4]);
            float4 b = *reinterpret_cast<const float4*>(
                &Wqz[(size_t)(c * 16 + k) * 256 + col0 + tn * 4]);
#pragma unroll
            for (int i = 0; i < 4; i++) {
                float ai = (i == 0) ? a.x : (i == 1) ? a.y : (i == 2) ? a.z : a.w;
                acc[i][0] += ai * b.x; acc[i][1] += ai * b.y;
                acc[i][2] += ai * b.z; acc[i][3] += ai * b.w;
            }
        }
    }
    float4 bv = *reinterpret_cast<const float4*>(&bz[col0 + tn * 4]);
#pragma unroll
    for (int i = 0; i < 4; i++) {
        float4 o = {acc[i][0] + bv.x, acc[i][1] + bv.y, acc[i][2] + bv.z, acc[i][3] + bv.w};
        *reinterpret_cast<float4*>(&zq[(size_t)(row0 + tm * 4 + i) * 256 + col0 + tn * 4]) = o;
    }
}

// ---------------------------------------------------------------------------
// cvec_kernel: cbuf[s] = ctx[s,:].wc + c0
// ---------------------------------------------------------------------------
__global__ __launch_bounds__(256) void cvec_kernel(
    const float* __restrict__ ctx, const float* __restrict__ wc,
    const float* __restrict__ c0, float* __restrict__ cbuf) {
    const int tid = threadIdx.x;
    const int row = blockIdx.x * 32 + (tid >> 3);
    const int l = tid & 7;
    float s = 0.f;
    for (int i = 0; i < 64; i += 4) {
        float4 a = *reinterpret_cast<const float4*>(&ctx[(size_t)row * 512 + l * 64 + i]);
        float4 b = *reinterpret_cast<const float4*>(&wc[l * 64 + i]);
        s += a.x * b.x + a.y * b.y + a.z * b.z + a.w * b.w;
    }
    s += __shfl_xor(s, 1); s += __shfl_xor(s, 2); s += __shfl_xor(s, 4);
    if (l == 0) cbuf[row] = s + c0[0];
}

// ---------------------------------------------------------------------------
// mlp_kernel: fused MLP, M=64 per block, 4 waves (1M x 4N), 33 KB LDS.
// 4 blocks/CU (vs 2 with M=128) -> 4 independent barrier domains per CU so
// one block's stage-X / epilogue latency overlaps another's MFMA phase.
// Swizzle (all K): elem(m,k) at m*K + ((k>>3)^(m&15))*8 + (k&7).
// MFMA operand swap: D = W_frag x act_frag -> lane holds 4 consecutive n.
// logits folded into layer-2 epilogue via zq (no k-GEMM).
// Register budget: __launch_bounds__(256,4) = 128 unified VGPR+AGPR:
// acc 64 (AGPR) + W double-buffer 32 + A single-buffer 16 + addressing fits.
// ---------------------------------------------------------------------------
template <int K>
__device__ __forceinline__ void run_layer(
    const short* __restrict__ act, const short* __restrict__ Wt,
    int nbase, int l16, int quad, f32x4 acc[4][4]) {
    constexpr int KK = K / 32;
    const f32x4 zero = {0.f, 0.f, 0.f, 0.f};
#pragma unroll
    for (int i = 0; i < 4; i++)
#pragma unroll
        for (int j = 0; j < 4; j++) acc[i][j] = zero;

    int woff[4];
#pragma unroll
    for (int ns = 0; ns < 4; ns++)
        woff[ns] = ((nbase + ns * 16 + l16) * K + quad * 8) * 2;
    const int abase = l16 * K * 2;   // ms sub-tiles via compile-time ds offset
    const char* actc = reinterpret_cast<const char*>(act);
    const char* wtc  = reinterpret_cast<const char*>(Wt);

    short8 wbuf[2][4];   // W double-buffered (L2 latency)
    short8 areg[4];      // A single-buffered (LDS latency, hidden by TLP)

#pragma unroll
    for (int ns = 0; ns < 4; ns++)
        wbuf[0][ns] = *reinterpret_cast<const short8*>(wtc + woff[ns]);

#pragma unroll
    for (int kk = 0; kk < KK; kk++) {
        // A fragments from LDS (swizzled) for this step
        {
            const int sg = (((kk * 4 + quad) ^ l16) * 16);
#pragma unroll
            for (int ms = 0; ms < 4; ms++)
                areg[ms] = *reinterpret_cast<const short8*>(
                    actc + abase + ms * 16 * K * 2 + sg);
        }
        // prefetch next W tile (kk+1 folds into the 13-bit global imm offset)
        if (kk + 1 < KK) {
#pragma unroll
            for (int ns = 0; ns < 4; ns++)
                wbuf[(kk + 1) & 1][ns] = *reinterpret_cast<const short8*>(
                    wtc + woff[ns] + (kk + 1) * 64);
        }
        const int cb = kk & 1;
#pragma unroll
        for (int ms = 0; ms < 4; ms++)
#pragma unroll
            for (int ns = 0; ns < 4; ns++)
                acc[ms][ns] = __builtin_amdgcn_mfma_f32_16x16x32_bf16(
                    wbuf[cb][ns], areg[ms], acc[ms][ns], 0, 0, 0);
    }
}

__global__ __launch_bounds__(256, 4) void mlp_kernel(
    const float* __restrict__ objects, const int* __restrict__ seg_ids,
    const short* __restrict__ W1T, const short* __restrict__ W2T,
    const short* __restrict__ W3vT,
    const float* __restrict__ b1, const float* __restrict__ b2,
    const float* __restrict__ b3,
    const float* __restrict__ zqbuf, const float* __restrict__ cbuf,
    float* __restrict__ logits_out, short* __restrict__ vout) {
    __shared__ __align__(16) short bufH[64 * 256];   // 32 KB: X -> h1 -> h2 -> v
    __shared__ float slots[4][64];

    const int tid  = threadIdx.x;
    const int wave = tid >> 6;
    const int lane = tid & 63;
    const int quad = lane >> 4;
    const int l16  = lane & 15;
    const int nbase = wave * 64;
    const int row0  = blockIdx.x * 64;

    // ---- stage X (fp32 -> bf16, K=128 swizzled layout in bufH[0:16KB])
    {
        const float4* op = reinterpret_cast<const float4*>(objects + (size_t)row0 * 128);
#pragma unroll
        for (int i = 0; i < 4; i++) {
            int u = tid + i * 256;           // 0..1023: m = u>>4, kg = u&15
            int m = u >> 4, kg = u & 15;
            float4 x0 = op[u * 2];
            float4 x1 = op[u * 2 + 1];
            short8 s;
            s[0] = f2bf(x0.x); s[1] = f2bf(x0.y); s[2] = f2bf(x0.z); s[3] = f2bf(x0.w);
            s[4] = f2bf(x1.x); s[5] = f2bf(x1.y); s[6] = f2bf(x1.z); s[7] = f2bf(x1.w);
            *reinterpret_cast<short8*>(&bufH[m * 128 + ((kg ^ (m & 15)) * 8)]) = s;
        }
    }
    __syncthreads();

    f32x4 acc[4][4];

    auto store_act = [&](const float* __restrict__ bias) {
#pragma unroll
        for (int ns = 0; ns < 4; ns++) {
            int n0 = nbase + ns * 16 + quad * 4;
            float4 bv = *reinterpret_cast<const float4*>(&bias[n0]);
#pragma unroll
            for (int ms = 0; ms < 4; ms++) {
                int m = ms * 16 + l16;
                short4 s;
                s.x = f2bf(fmaxf(acc[ms][ns][0] + bv.x, 0.f));
                s.y = f2bf(fmaxf(acc[ms][ns][1] + bv.y, 0.f));
                s.z = f2bf(fmaxf(acc[ms][ns][2] + bv.z, 0.f));
                s.w = f2bf(fmaxf(acc[ms][ns][3] + bv.w, 0.f));
                *reinterpret_cast<short4*>(
                    &bufH[m * 256 + (((n0 >> 3) ^ (m & 15)) * 8) + (n0 & 7)]) = s;
            }
        }
    };

    // ---- layer 1: h1 = relu(X @ W1 + b1)
    run_layer<128>(bufH, W1T, nbase, l16, quad, acc);
    __syncthreads();                 // X fully consumed
    store_act(b1);
    __syncthreads();

    // ---- layer 2: h2 = relu(h1 @ W2 + b2); fold logits = h2.zq[seg]
    run_layer<256>(bufH, W2T, nbase, l16, quad, acc);
    __syncthreads();                 // h1 fully consumed
    {
        float part[4] = {0.f, 0.f, 0.f, 0.f};
        int segm[4];
#pragma unroll
        for (int ms = 0; ms < 4; ms++) segm[ms] = seg_ids[row0 + ms * 16 + l16];
#pragma unroll
        for (int ns = 0; ns < 4; ns++) {
            int n0 = nbase + ns * 16 + quad * 4;
            float4 bv = *reinterpret_cast<const float4*>(&b2[n0]);
#pragma unroll
            for (int ms = 0; ms < 4; ms++) {
                int m = ms * 16 + l16;
                float h0 = fmaxf(acc[ms][ns][0] + bv.x, 0.f);
                float h1v = fmaxf(acc[ms][ns][1] + bv.y, 0.f);
                float h2v = fmaxf(acc[ms][ns][2] + bv.z, 0.f);
                float h3 = fmaxf(acc[ms][ns][3] + bv.w, 0.f);
                short4 s;
                s.x = f2bf(h0); s.y = f2bf(h1v); s.z = f2bf(h2v); s.w = f2bf(h3);
                *reinterpret_cast<short4*>(
                    &bufH[m * 256 + (((n0 >> 3) ^ (m & 15)) * 8) + (n0 & 7)]) = s;
                float4 zq4 = *reinterpret_cast<const float4*>(
                    &zqbuf[(size_t)segm[ms] * 256 + n0]);
                part[ms] += h0 * zq4.x + h1v * zq4.y + h2v * zq4.z + h3 * zq4.w;
            }
        }
#pragma unroll
        for (int ms = 0; ms < 4; ms++) {
            float p = part[ms];
            p += __shfl_xor(p, 16);
            p += __shfl_xor(p, 32);
            if (quad == 0) slots[wave][ms * 16 + l16] = p;
        }
    }
    __syncthreads();
    if (tid < 64) {
        int seg = seg_ids[row0 + tid];
        float s = slots[0][tid] + slots[1][tid] + slots[2][tid] + slots[3][tid] + cbuf[seg];
        logits_out[row0 + tid] = s * 0.0625f;   // / sqrt(256)
    }

    // ---- layer 3 v-half: v = h2 @ W3v + b3v
    run_layer<256>(bufH, W3vT, nbase, l16, quad, acc);
    __syncthreads();                 // h2 fully consumed
#pragma unroll
    for (int ns = 0; ns < 4; ns++) {
        int n0 = nbase + ns * 16 + quad * 4;
        float4 bv = *reinterpret_cast<const float4*>(&b3[256 + n0]);
#pragma unroll
        for (int ms = 0; ms < 4; ms++) {
            int m = ms * 16 + l16;
            short4 s;
            s.x = f2bf(acc[ms][ns][0] + bv.x);
            s.y = f2bf(acc[ms][ns][1] + bv.y);
            s.z = f2bf(acc[ms][ns][2] + bv.z);
            s.w = f2bf(acc[ms][ns][3] + bv.w);
            *reinterpret_cast<short4*>(
                &bufH[m * 256 + (((n0 >> 3) ^ (m & 15)) * 8) + (n0 & 7)]) = s;
        }
    }
    __syncthreads();
    // copy out, un-swizzling
#pragma unroll
    for (int i = 0; i < 8; i++) {
        int idx = tid + i * 256;          // [0,2048): m = idx>>5, sg = idx&31
        int m = idx >> 5, sg = idx & 31;
        short8 val = *reinterpret_cast<const short8*>(&bufH[m * 256 + sg * 8]);
        int n0 = (sg ^ (m & 15)) * 8;
        *reinterpret_cast<short8*>(&vout[(size_t)(row0 + m) * 256 + n0]) = val;
    }
}

// ---------------------------------------------------------------------------
// seg_starts_kernel: starts[s] = first t with seg_ids[t] == s (segments are
// sorted and non-empty). Runs AFTER mlp (reuses the dead cbuf region).
// ---------------------------------------------------------------------------
__global__ __launch_bounds__(256) void seg_starts_kernel(
    const int* __restrict__ seg, int* __restrict__ starts) {
    int t = blockIdx.x * 256 + threadIdx.x;
    if (t >= T_TOTAL) return;
    int s = seg[t];
    if (t == 0) {
        for (int q = 0; q <= s; q++) starts[q] = 0;
    } else {
        int p = seg[t - 1];
        for (int q = p + 1; q <= s; q++) starts[q] = t;
    }
}

// ---------------------------------------------------------------------------
// segment_kernel: per-segment softmax + weighted sum of v.
// One wave per segment: no LDS, no barriers, no binary search; v-sum keeps
// 8 rows (8 x 8B per lane) in flight to cover L3 latency.
// ---------------------------------------------------------------------------
__global__ __launch_bounds__(64) void segment_kernel(
    const float* __restrict__ logits, const short* __restrict__ vbuf,
    const int* __restrict__ starts, float* __restrict__ emb,
    float* __restrict__ wout) {
    const int b = blockIdx.x;
    const int lane = threadIdx.x;
    const int start = starts[b];
    const int end = (b == B_SEG - 1) ? T_TOTAL : starts[b + 1];

    float mx = -1e30f;
    for (int t = start + lane; t < end; t += 64) mx = fmaxf(mx, logits[t]);
#pragma unroll
    for (int off = 32; off >= 1; off >>= 1) mx = fmaxf(mx, __shfl_xor(mx, off));

    float s = 0.f;
    for (int t = start + lane; t < end; t += 64) s += __expf(logits[t] - mx);
#pragma unroll
    for (int off = 32; off >= 1; off >>= 1) s += __shfl_xor(s, off);
    const float invz = 1.f / s;

    for (int t = start + lane; t < end; t += 64)
        wout[t] = __expf(logits[t] - mx) * invz;

    // weighted v-sum: lane covers cols lane*4 .. lane*4+3 (wave reads full
    // 512B row); unroll 8 rows for memory-level parallelism.
    float a[4][4];
#pragma unroll
    for (int i = 0; i < 4; i++)
#pragma unroll
        for (int j = 0; j < 4; j++) a[i][j] = 0.f;

    int t = start;
    for (; t + 8 <= end; t += 8) {
#pragma unroll
        for (int u = 0; u < 8; u++) {
            float wv = __expf(logits[t + u] - mx) * invz;
            short4 v4 = *reinterpret_cast<const short4*>(
                &vbuf[(size_t)(t + u) * 256 + lane * 4]);
            a[u & 3][0] += wv * bf2f(v4.x);
            a[u & 3][1] += wv * bf2f(v4.y);
            a[u & 3][2] += wv * bf2f(v4.z);
            a[u & 3][3] += wv * bf2f(v4.w);
        }
    }
    for (; t < end; t++) {
        float wv = __expf(logits[t] - mx) * invz;
        short4 v4 = *reinterpret_cast<const short4*>(
            &vbuf[(size_t)t * 256 + lane * 4]);
        a[0][0] += wv * bf2f(v4.x);
        a[0][1] += wv * bf2f(v4.y);
        a[0][2] += wv * bf2f(v4.z);
        a[0][3] += wv * bf2f(v4.w);
    }
    float4 o;
    o.x = a[0][0] + a[1][0] + a[2][0] + a[3][0];
    o.y = a[0][1] + a[1][1] + a[2][1] + a[3][1];
    o.z = a[0][2] + a[1][2] + a[2][2] + a[3][2];
    o.w = a[0][3] + a[1][3] + a[2][3] + a[3][3];
    *reinterpret_cast<float4*>(&emb[(size_t)b * 256 + lane * 4]) = o;
}

// ---------------------------------------------------------------------------
extern "C" void kernel_launch(void* const* d_in, const int* in_sizes, int n_in,
                              void* d_out, int out_size, void* d_ws, size_t ws_size,
                              hipStream_t stream) {
    const float* objects = (const float*)d_in[0];
    const float* context = (const float*)d_in[1];
    const int*   seg     = (const int*)d_in[2];
    const float* W1 = (const float*)d_in[3];
    const float* b1 = (const float*)d_in[4];
    const float* W2 = (const float*)d_in[5];
    const float* b2 = (const float*)d_in[6];
    const float* W3 = (const float*)d_in[7];
    const float* b3 = (const float*)d_in[8];
    const float* Wq = (const float*)d_in[9];
    const float* bq = (const float*)d_in[10];

    char* ws = (char*)d_ws;
    float* zqbuf = (float*)(ws);                        // 4 MB
    float* cbuf  = (float*)(ws + 4194304);              // 16 KB (dead after mlp)
    int*   seg_starts = (int*)(ws + 4194304);           // overlays cbuf post-mlp
    short* W1T   = (short*)(ws + 4210688);              // 64 KB
    short* W2T   = (short*)(ws + 4276224);              // 128 KB
    short* W3vT  = (short*)(ws + 4407296);              // 128 KB
    // logits region (1 MB) doubles as scratch for Wqz/bz/wc/c0 (consumed
    // before mlp_kernel writes logits over it)
    char*  lreg   = ws + 4538368;
    float* logits = (float*)lreg;
    float* Wqz    = (float*)lreg;                       // 512 KB
    float* bz     = (float*)(lreg + 524288);            // 1 KB
    float* wc     = (float*)(lreg + 525312);            // 2 KB
    float* c0     = (float*)(lreg + 527360);            // 16 B
    short* vbuf   = (short*)(ws + 5586944);             // 128 MB

    float* emb  = (float*)d_out;
    float* wout = emb + (size_t)B_SEG * 256;

    transpose_weights<<<40, 256, 0, stream>>>(W1, W2, W3, W1T, W2T, W3vT);
    vec_kernel<<<2, 256, 0, stream>>>(Wq, W3, bq, b3, bz, wc, c0);
    prep_wqz<<<512, 256, 0, stream>>>(Wq, W3, Wqz);
    zq_kernel<<<dim3(64, 4), 256, 0, stream>>>(context, Wqz, bz, zqbuf);
    cvec_kernel<<<128, 256, 0, stream>>>(context, wc, c0, cbuf);
    mlp_kernel<<<T_TOTAL / 64, 256, 0, stream>>>(objects, seg, W1T, W2T, W3vT,
                                                 b1, b2, b3, zqbuf, cbuf,
                                                 logits, vbuf);
    seg_starts_kernel<<<T_TOTAL / 256, 256, 0, stream>>>(seg, seg_starts);
    segment_kernel<<<B_SEG, 64, 0, stream>>>(logits, vbuf, seg_starts, emb, wout);
}

// Round 3
// 450.921 us; speedup vs baseline: 1.1353x; 1.0704x over previous
//
#include <hip/hip_runtime.h>
#include <hip/hip_bf16.h>

#define T_TOTAL 262144
#define B_SEG   4096

typedef __attribute__((ext_vector_type(8))) short short8;
typedef __attribute__((ext_vector_type(4))) float f32x4;

__device__ __forceinline__ short f2bf(float x) {
    __hip_bfloat16 h = __float2bfloat16(x);
    return *reinterpret_cast<short*>(&h);
}
__device__ __forceinline__ float bf2f(short s) {
    unsigned u = ((unsigned)(unsigned short)s) << 16;
    return __uint_as_float(u);
}

// ---------------------------------------------------------------------------
// prep_all: merged independent prep work (one launch instead of four).
//   blocks [0,40):   transpose W1/W2/W3v -> bf16 [N][K]
//   blocks [40,42):  vec_kernel (bz / wc / c0)
//   blocks [42,554): prep_wqz  (Wqz = Wq . W3k^T, 16x16 tiles)
//   blocks [554,682): cvec (cbuf[s] = ctx[s].wc + c0)
// ---------------------------------------------------------------------------
__global__ __launch_bounds__(256) void prep_all(
    const float* __restrict__ W1, const float* __restrict__ W2,
    const float* __restrict__ W3, const float* __restrict__ Wq,
    const float* __restrict__ bq, const float* __restrict__ b3,
    const float* __restrict__ ctx,
    short* __restrict__ W1T, short* __restrict__ W2T, short* __restrict__ W3vT,
    float* __restrict__ bz, float* __restrict__ wc, float* __restrict__ c0,
    float* __restrict__ Wqz, float* __restrict__ cbuf) {
    __shared__ __align__(16) char smem[33280];
    const int b = blockIdx.x, tid = threadIdx.x;

    if (b < 40) {
        // ---- transpose_weights
        float (*t)[68] = reinterpret_cast<float(*)[68]>(smem);
        const float* src; short* dst;
        int k0, n0_src, n0_dst, sstride, dstride;
        if (b < 8) {
            int kt = b >> 2, nt = b & 3;
            src = W1; dst = W1T; sstride = 256; dstride = 128;
            k0 = kt * 64; n0_src = nt * 64; n0_dst = nt * 64;
        } else if (b < 24) {
            int id = b - 8, kt = id >> 2, nt = id & 3;
            src = W2; dst = W2T; sstride = 256; dstride = 256;
            k0 = kt * 64; n0_src = nt * 64; n0_dst = nt * 64;
        } else {
            int id = b - 24, kt = id >> 2, nt = id & 3;
            src = W3; dst = W3vT; sstride = 512; dstride = 256;
            k0 = kt * 64; n0_src = 256 + nt * 64; n0_dst = nt * 64;
        }
        {
            int r = tid >> 4, c4 = (tid & 15) * 4;
#pragma unroll
            for (int p = 0; p < 4; p++) {
                int k = p * 16 + r;
                float4 v = *reinterpret_cast<const float4*>(
                    &src[(size_t)(k0 + k) * sstride + n0_src + c4]);
                *reinterpret_cast<float4*>(&t[k][c4]) = v;
            }
        }
        __syncthreads();
        {
            int n = tid >> 2, kq = tid & 3;
            short8 s0, s1;
#pragma unroll
            for (int i = 0; i < 8; i++) s0[i] = f2bf(t[kq * 16 + i][n]);
#pragma unroll
            for (int i = 0; i < 8; i++) s1[i] = f2bf(t[kq * 16 + 8 + i][n]);
            short* o = &dst[(size_t)(n0_dst + n) * dstride + k0 + kq * 16];
            *reinterpret_cast<short8*>(o) = s0;
            *reinterpret_cast<short8*>(o + 8) = s1;
        }
    } else if (b < 42) {
        // ---- vec_kernel
        if (b == 40) {
            float s = 0.f;
            for (int n = 0; n < 256; n += 4) {
                float4 a = *reinterpret_cast<const float4*>(&W3[(size_t)tid * 512 + n]);
                float4 v = *reinterpret_cast<const float4*>(&bq[n]);
                s += a.x * v.x + a.y * v.y + a.z * v.z + a.w * v.w;
            }
            bz[tid] = s;
        } else {
#pragma unroll
            for (int h = 0; h < 2; h++) {
                int c = h * 256 + tid;
                float s = 0.f;
                for (int n = 0; n < 256; n += 4) {
                    float4 a = *reinterpret_cast<const float4*>(&Wq[(size_t)c * 256 + n]);
                    float4 v = *reinterpret_cast<const float4*>(&b3[n]);
                    s += a.x * v.x + a.y * v.y + a.z * v.z + a.w * v.w;
                }
                wc[c] = s;
            }
            if (tid == 0) {
                float s = 0.f;
                for (int n = 0; n < 256; n++) s += bq[n] * b3[n];
                c0[0] = s;
            }
        }
    } else if (b < 554) {
        // ---- prep_wqz
        float (*wq)[260] = reinterpret_cast<float(*)[260]>(smem);
        float (*w3)[260] = reinterpret_cast<float(*)[260]>(smem + 16640);
        const int id = b - 42;
        const int c0r = (id >> 4) * 16, j0 = (id & 15) * 16;
        {
            int r = tid >> 4, nq = tid & 15;
#pragma unroll
            for (int p = 0; p < 4; p++) {
                int col = nq * 4 + p * 64;
                *reinterpret_cast<float4*>(&wq[r][col]) =
                    *reinterpret_cast<const float4*>(&Wq[(size_t)(c0r + r) * 256 + col]);
                *reinterpret_cast<float4*>(&w3[r][col]) =
                    *reinterpret_cast<const float4*>(&W3[(size_t)(j0 + r) * 512 + col]);
            }
        }
        __syncthreads();
        const int ci = tid >> 4, ji = tid & 15;
        float s = 0.f;
        for (int n = 0; n < 256; n += 4) {
            float4 a = *reinterpret_cast<const float4*>(&wq[ci][n]);
            float4 v = *reinterpret_cast<const float4*>(&w3[ji][n]);
            s += a.x * v.x + a.y * v.y + a.z * v.z + a.w * v.w;
        }
        Wqz[(size_t)(c0r + ci) * 256 + j0 + ji] = s;
    } else {
        // ---- cvec
        const int id = b - 554;
        const int row = id * 32 + (tid >> 3);
        const int l = tid & 7;
        float s = 0.f;
        for (int i = 0; i < 64; i += 4) {
            float4 a = *reinterpret_cast<const float4*>(&ctx[(size_t)row * 512 + l * 64 + i]);
            float4 v = *reinterpret_cast<const float4*>(&wc[l * 64 + i]);
            s += a.x * v.x + a.y * v.y + a.z * v.z + a.w * v.w;
        }
        s += __shfl_xor(s, 1); s += __shfl_xor(s, 2); s += __shfl_xor(s, 4);
        if (l == 0) cbuf[row] = s + c0[0];
    }
}

// ---------------------------------------------------------------------------
// zq_kernel: ZQ = context @ Wqz + bz  (fp32 [4096][256]); 64x64 tile SGEMM
// ---------------------------------------------------------------------------
__global__ __launch_bounds__(256) void zq_kernel(
    const float* __restrict__ ctx, const float* __restrict__ Wqz,
    const float* __restrict__ bz, float* __restrict__ zq) {
    __shared__ float As[2][16][68];
    const int tid = threadIdx.x;
    const int tm = tid & 15, tn = tid >> 4;
    const int row0 = blockIdx.x * 64, col0 = blockIdx.y * 64;
    const int lr = tid >> 2, lk = tid & 3;

    float acc[4][4];
#pragma unroll
    for (int i = 0; i < 4; i++)
#pragma unroll
        for (int j = 0; j < 4; j++) acc[i][j] = 0.f;

    float4 av = *reinterpret_cast<const float4*>(&ctx[(size_t)(row0 + lr) * 512 + lk * 4]);
    for (int c = 0; c < 32; c++) {
        int cur = c & 1;
        As[cur][lk * 4 + 0][lr] = av.x;
        As[cur][lk * 4 + 1][lr] = av.y;
        As[cur][lk * 4 + 2][lr] = av.z;
        As[cur][lk * 4 + 3][lr] = av.w;
        __syncthreads();
        if (c < 31)
            av = *reinterpret_cast<const float4*>(
                &ctx[(size_t)(row0 + lr) * 512 + (c + 1) * 16 + lk * 4]);
#pragma unroll
        for (int k = 0; k < 16; k++) {
            float4 a = *reinterpret_cast<const float4*>(&As[cur][k][tm * 4]);
            float4 b = *reinterpret_cast<const float4*>(
                &Wqz[(size_t)(c * 16 + k) * 256 + col0 + tn * 4]);
#pragma unroll
            for (int i = 0; i < 4; i++) {
                float ai = (i == 0) ? a.x : (i == 1) ? a.y : (i == 2) ? a.z : a.w;
                acc[i][0] += ai * b.x; acc[i][1] += ai * b.y;
                acc[i][2] += ai * b.z; acc[i][3] += ai * b.w;
            }
        }
    }
    float4 bv = *reinterpret_cast<const float4*>(&bz[col0 + tn * 4]);
#pragma unroll
    for (int i = 0; i < 4; i++) {
        float4 o = {acc[i][0] + bv.x, acc[i][1] + bv.y, acc[i][2] + bv.z, acc[i][3] + bv.w};
        *reinterpret_cast<float4*>(&zq[(size_t)(row0 + tm * 4 + i) * 256 + col0 + tn * 4]) = o;
    }
}

// ---------------------------------------------------------------------------
// mlp_kernel: fused MLP, M=64 per block, 4 waves (1M x 4N), 33 KB LDS.
// __launch_bounds__(256,3): ~168 VGPR/wave -> acc(64) + W dbuf(32) + A dbuf(32)
// + addressing fit with NO spills (R1/R2 at 4 waves/EU spilled ~25KB/block,
// visible as +25KB/block WRITE_SIZE). 2-step-ahead W prefetch covers L2
// latency (~250cyc) that a 1-step prefetch exposed every kk-step.
// Swizzle (all K): elem(m,k) at m*K + ((k>>3)^(m&15))*8 + (k&7).
// MFMA operand swap: D = W_frag x act_frag -> lane holds 4 consecutive n.
// ---------------------------------------------------------------------------
template <int K>
__device__ __forceinline__ void run_layer(
    const short* __restrict__ act, const short* __restrict__ Wt,
    int nbase, int l16, int quad, f32x4 acc[4][4]) {
    constexpr int KK = K / 32;
    const f32x4 zero = {0.f, 0.f, 0.f, 0.f};
#pragma unroll
    for (int i = 0; i < 4; i++)
#pragma unroll
        for (int j = 0; j < 4; j++) acc[i][j] = zero;

    int woff[4];
#pragma unroll
    for (int ns = 0; ns < 4; ns++)
        woff[ns] = ((nbase + ns * 16 + l16) * K + quad * 8) * 2;
    const int abase = l16 * K * 2;   // ms sub-tiles via compile-time ds offset
    const char* actc = reinterpret_cast<const char*>(act);
    const char* wtc  = reinterpret_cast<const char*>(Wt);

    short8 wbuf[2][4];
    short8 areg[2][4];

    auto loadA = [&](int kk, int slot) {
        const int sg = (((kk * 4 + quad) ^ l16) * 16);
#pragma unroll
        for (int ms = 0; ms < 4; ms++)
            areg[slot][ms] = *reinterpret_cast<const short8*>(
                actc + abase + ms * 16 * K * 2 + sg);
    };
    auto loadW = [&](int kk, int slot) {
#pragma unroll
        for (int ns = 0; ns < 4; ns++)
            wbuf[slot][ns] = *reinterpret_cast<const short8*>(
                wtc + woff[ns] + kk * 64);
    };

    loadW(0, 0); loadA(0, 0);
    loadW(1, 1); loadA(1, 1);
#pragma unroll
    for (int kk = 0; kk < KK; kk++) {
        const int cur = kk & 1;
#pragma unroll
        for (int ms = 0; ms < 4; ms++)
#pragma unroll
            for (int ns = 0; ns < 4; ns++)
                acc[ms][ns] = __builtin_amdgcn_mfma_f32_16x16x32_bf16(
                    wbuf[cur][ns], areg[cur][ms], acc[ms][ns], 0, 0, 0);
        if (kk + 2 < KK) { loadW(kk + 2, cur); loadA(kk + 2, cur); }
    }
}

__global__ __launch_bounds__(256, 3) void mlp_kernel(
    const float* __restrict__ objects, const int* __restrict__ seg_ids,
    const short* __restrict__ W1T, const short* __restrict__ W2T,
    const short* __restrict__ W3vT,
    const float* __restrict__ b1, const float* __restrict__ b2,
    const float* __restrict__ b3,
    const float* __restrict__ zqbuf, const float* __restrict__ cbuf,
    float* __restrict__ logits_out, short* __restrict__ vout) {
    __shared__ __align__(16) short bufH[64 * 256];   // 32 KB: X -> h1 -> h2 -> v
    __shared__ float slots[4][64];

    const int tid  = threadIdx.x;
    const int wave = tid >> 6;
    const int lane = tid & 63;
    const int quad = lane >> 4;
    const int l16  = lane & 15;
    const int nbase = wave * 64;
    const int row0  = blockIdx.x * 64;

    // ---- stage X (fp32 -> bf16, K=128 swizzled layout in bufH[0:16KB])
    {
        const float4* op = reinterpret_cast<const float4*>(objects + (size_t)row0 * 128);
#pragma unroll
        for (int i = 0; i < 4; i++) {
            int u = tid + i * 256;           // 0..1023: m = u>>4, kg = u&15
            int m = u >> 4, kg = u & 15;
            float4 x0 = op[u * 2];
            float4 x1 = op[u * 2 + 1];
            short8 s;
            s[0] = f2bf(x0.x); s[1] = f2bf(x0.y); s[2] = f2bf(x0.z); s[3] = f2bf(x0.w);
            s[4] = f2bf(x1.x); s[5] = f2bf(x1.y); s[6] = f2bf(x1.z); s[7] = f2bf(x1.w);
            *reinterpret_cast<short8*>(&bufH[m * 128 + ((kg ^ (m & 15)) * 8)]) = s;
        }
    }
    __syncthreads();

    f32x4 acc[4][4];

    auto store_act = [&](const float* __restrict__ bias) {
#pragma unroll
        for (int ns = 0; ns < 4; ns++) {
            int n0 = nbase + ns * 16 + quad * 4;
            float4 bv = *reinterpret_cast<const float4*>(&bias[n0]);
#pragma unroll
            for (int ms = 0; ms < 4; ms++) {
                int m = ms * 16 + l16;
                short4 s;
                s.x = f2bf(fmaxf(acc[ms][ns][0] + bv.x, 0.f));
                s.y = f2bf(fmaxf(acc[ms][ns][1] + bv.y, 0.f));
                s.z = f2bf(fmaxf(acc[ms][ns][2] + bv.z, 0.f));
                s.w = f2bf(fmaxf(acc[ms][ns][3] + bv.w, 0.f));
                *reinterpret_cast<short4*>(
                    &bufH[m * 256 + (((n0 >> 3) ^ (m & 15)) * 8) + (n0 & 7)]) = s;
            }
        }
    };

    // ---- layer 1: h1 = relu(X @ W1 + b1)
    run_layer<128>(bufH, W1T, nbase, l16, quad, acc);
    __syncthreads();                 // X fully consumed
    store_act(b1);
    __syncthreads();

    // ---- layer 2: h2 = relu(h1 @ W2 + b2); fold logits = h2.zq[seg]
    run_layer<256>(bufH, W2T, nbase, l16, quad, acc);
    __syncthreads();                 // h1 fully consumed
    {
        float part[4] = {0.f, 0.f, 0.f, 0.f};
        int segm[4];
#pragma unroll
        for (int ms = 0; ms < 4; ms++) segm[ms] = seg_ids[row0 + ms * 16 + l16];
#pragma unroll
        for (int ns = 0; ns < 4; ns++) {
            int n0 = nbase + ns * 16 + quad * 4;
            float4 bv = *reinterpret_cast<const float4*>(&b2[n0]);
#pragma unroll
            for (int ms = 0; ms < 4; ms++) {
                int m = ms * 16 + l16;
                float h0 = fmaxf(acc[ms][ns][0] + bv.x, 0.f);
                float h1v = fmaxf(acc[ms][ns][1] + bv.y, 0.f);
                float h2v = fmaxf(acc[ms][ns][2] + bv.z, 0.f);
                float h3 = fmaxf(acc[ms][ns][3] + bv.w, 0.f);
                short4 s;
                s.x = f2bf(h0); s.y = f2bf(h1v); s.z = f2bf(h2v); s.w = f2bf(h3);
                *reinterpret_cast<short4*>(
                    &bufH[m * 256 + (((n0 >> 3) ^ (m & 15)) * 8) + (n0 & 7)]) = s;
                float4 zq4 = *reinterpret_cast<const float4*>(
                    &zqbuf[(size_t)segm[ms] * 256 + n0]);
                part[ms] += h0 * zq4.x + h1v * zq4.y + h2v * zq4.z + h3 * zq4.w;
            }
        }
#pragma unroll
        for (int ms = 0; ms < 4; ms++) {
            float p = part[ms];
            p += __shfl_xor(p, 16);
            p += __shfl_xor(p, 32);
            if (quad == 0) slots[wave][ms * 16 + l16] = p;
        }
    }
    __syncthreads();
    if (tid < 64) {
        int seg = seg_ids[row0 + tid];
        float s = slots[0][tid] + slots[1][tid] + slots[2][tid] + slots[3][tid] + cbuf[seg];
        logits_out[row0 + tid] = s * 0.0625f;   // / sqrt(256)
    }

    // ---- layer 3 v-half: v = h2 @ W3v + b3v
    run_layer<256>(bufH, W3vT, nbase, l16, quad, acc);
    __syncthreads();                 // h2 fully consumed
#pragma unroll
    for (int ns = 0; ns < 4; ns++) {
        int n0 = nbase + ns * 16 + quad * 4;
        float4 bv = *reinterpret_cast<const float4*>(&b3[256 + n0]);
#pragma unroll
        for (int ms = 0; ms < 4; ms++) {
            int m = ms * 16 + l16;
            short4 s;
            s.x = f2bf(acc[ms][ns][0] + bv.x);
            s.y = f2bf(acc[ms][ns][1] + bv.y);
            s.z = f2bf(acc[ms][ns][2] + bv.z);
            s.w = f2bf(acc[ms][ns][3] + bv.w);
            *reinterpret_cast<short4*>(
                &bufH[m * 256 + (((n0 >> 3) ^ (m & 15)) * 8) + (n0 & 7)]) = s;
        }
    }
    __syncthreads();
    // copy out, un-swizzling
#pragma unroll
    for (int i = 0; i < 8; i++) {
        int idx = tid + i * 256;          // [0,2048): m = idx>>5, sg = idx&31
        int m = idx >> 5, sg = idx & 31;
        short8 val = *reinterpret_cast<const short8*>(&bufH[m * 256 + sg * 8]);
        int n0 = (sg ^ (m & 15)) * 8;
        *reinterpret_cast<short8*>(&vout[(size_t)(row0 + m) * 256 + n0]) = val;
    }
}

// ---------------------------------------------------------------------------
// seg_starts_kernel: starts[s] = first t with seg_ids[t] == s
// ---------------------------------------------------------------------------
__global__ __launch_bounds__(256) void seg_starts_kernel(
    const int* __restrict__ seg, int* __restrict__ starts) {
    int t = blockIdx.x * 256 + threadIdx.x;
    if (t >= T_TOTAL) return;
    int s = seg[t];
    if (t == 0) {
        for (int q = 0; q <= s; q++) starts[q] = 0;
    } else {
        int p = seg[t - 1];
        for (int q = p + 1; q <= s; q++) starts[q] = t;
    }
}

// ---------------------------------------------------------------------------
// segment_kernel: per-segment softmax + weighted sum of v. One wave/segment.
// ---------------------------------------------------------------------------
__global__ __launch_bounds__(64) void segment_kernel(
    const float* __restrict__ logits, const short* __restrict__ vbuf,
    const int* __restrict__ starts, float* __restrict__ emb,
    float* __restrict__ wout) {
    const int b = blockIdx.x;
    const int lane = threadIdx.x;
    const int start = starts[b];
    const int end = (b == B_SEG - 1) ? T_TOTAL : starts[b + 1];

    float mx = -1e30f;
    for (int t = start + lane; t < end; t += 64) mx = fmaxf(mx, logits[t]);
#pragma unroll
    for (int off = 32; off >= 1; off >>= 1) mx = fmaxf(mx, __shfl_xor(mx, off));

    float s = 0.f;
    for (int t = start + lane; t < end; t += 64) s += __expf(logits[t] - mx);
#pragma unroll
    for (int off = 32; off >= 1; off >>= 1) s += __shfl_xor(s, off);
    const float invz = 1.f / s;

    for (int t = start + lane; t < end; t += 64)
        wout[t] = __expf(logits[t] - mx) * invz;

    float a[4][4];
#pragma unroll
    for (int i = 0; i < 4; i++)
#pragma unroll
        for (int j = 0; j < 4; j++) a[i][j] = 0.f;

    int t = start;
    for (; t + 8 <= end; t += 8) {
#pragma unroll
        for (int u = 0; u < 8; u++) {
            float wv = __expf(logits[t + u] - mx) * invz;
            short4 v4 = *reinterpret_cast<const short4*>(
                &vbuf[(size_t)(t + u) * 256 + lane * 4]);
            a[u & 3][0] += wv * bf2f(v4.x);
            a[u & 3][1] += wv * bf2f(v4.y);
            a[u & 3][2] += wv * bf2f(v4.z);
            a[u & 3][3] += wv * bf2f(v4.w);
        }
    }
    for (; t < end; t++) {
        float wv = __expf(logits[t] - mx) * invz;
        short4 v4 = *reinterpret_cast<const short4*>(
            &vbuf[(size_t)t * 256 + lane * 4]);
        a[0][0] += wv * bf2f(v4.x);
        a[0][1] += wv * bf2f(v4.y);
        a[0][2] += wv * bf2f(v4.z);
        a[0][3] += wv * bf2f(v4.w);
    }
    float4 o;
    o.x = a[0][0] + a[1][0] + a[2][0] + a[3][0];
    o.y = a[0][1] + a[1][1] + a[2][1] + a[3][1];
    o.z = a[0][2] + a[1][2] + a[2][2] + a[3][2];
    o.w = a[0][3] + a[1][3] + a[2][3] + a[3][3];
    *reinterpret_cast<float4*>(&emb[(size_t)b * 256 + lane * 4]) = o;
}

// ---------------------------------------------------------------------------
extern "C" void kernel_launch(void* const* d_in, const int* in_sizes, int n_in,
                              void* d_out, int out_size, void* d_ws, size_t ws_size,
                              hipStream_t stream) {
    const float* objects = (const float*)d_in[0];
    const float* context = (const float*)d_in[1];
    const int*   seg     = (const int*)d_in[2];
    const float* W1 = (const float*)d_in[3];
    const float* b1 = (const float*)d_in[4];
    const float* W2 = (const float*)d_in[5];
    const float* b2 = (const float*)d_in[6];
    const float* W3 = (const float*)d_in[7];
    const float* b3 = (const float*)d_in[8];
    const float* Wq = (const float*)d_in[9];
    const float* bq = (const float*)d_in[10];

    char* ws = (char*)d_ws;
    float* zqbuf = (float*)(ws);                        // 4 MB
    float* cbuf  = (float*)(ws + 4194304);              // 16 KB (dead after mlp)
    int*   seg_starts = (int*)(ws + 4194304);           // overlays cbuf post-mlp
    short* W1T   = (short*)(ws + 4210688);              // 64 KB
    short* W2T   = (short*)(ws + 4276224);              // 128 KB
    short* W3vT  = (short*)(ws + 4407296);              // 128 KB
    // logits region (1 MB) doubles as scratch for Wqz/bz/wc/c0 (consumed
    // before mlp_kernel writes logits over it)
    char*  lreg   = ws + 4538368;
    float* logits = (float*)lreg;
    float* Wqz    = (float*)lreg;                       // 512 KB
    float* bz     = (float*)(lreg + 524288);            // 1 KB
    float* wc     = (float*)(lreg + 525312);            // 2 KB
    float* c0     = (float*)(lreg + 527360);            // 16 B
    short* vbuf   = (short*)(ws + 5586944);             // 128 MB

    float* emb  = (float*)d_out;
    float* wout = emb + (size_t)B_SEG * 256;

    prep_all<<<682, 256, 0, stream>>>(W1, W2, W3, Wq, bq, b3, context,
                                      W1T, W2T, W3vT, bz, wc, c0, Wqz, cbuf);
    zq_kernel<<<dim3(64, 4), 256, 0, stream>>>(context, Wqz, bz, zqbuf);
    mlp_kernel<<<T_TOTAL / 64, 256, 0, stream>>>(objects, seg, W1T, W2T, W3vT,
                                                 b1, b2, b3, zqbuf, cbuf,
                                                 logits, vbuf);
    seg_starts_kernel<<<T_TOTAL / 256, 256, 0, stream>>>(seg, seg_starts);
    segment_kernel<<<B_SEG, 64, 0, stream>>>(logits, vbuf, seg_starts, emb, wout);
}